// Round 1
// baseline (107164.929 us; speedup 1.0000x reference)
//
#include <hip/hip_runtime.h>

#define G4 4096

__device__ __forceinline__ float sigm(float x){ return 1.f/(1.f+__expf(-x)); }
__device__ __forceinline__ float ftanh(float x){
  x = fminf(fmaxf(x,-15.f),15.f);
  float e = __expf(2.f*x);
  return (e-1.f)/(e+1.f);
}

// -------------------- precompute --------------------

// h1[t*32+b][j] = relu(sum_c dec_in(t,b,c) * W1[c][j]);  dec_in(t,b,c)= t==0?0:mel_target[b][c][t-1]
__global__ __launch_bounds__(256) void prenet1_kernel(const float* __restrict__ mel_target,
    const float* __restrict__ W1, float* __restrict__ h1)
{
  __shared__ float din[80];
  int blk = blockIdx.x;          // t*32 + b
  int t = blk >> 5, b = blk & 31;
  int tid = threadIdx.x;
  if (tid < 80) din[tid] = (t==0) ? 0.f : mel_target[b*32000 + tid*400 + (t-1)];
  __syncthreads();
  float s=0.f;
  for (int c=0;c<80;c++) s += din[c]*W1[c*256+tid];
  h1[(size_t)blk*256 + tid] = fmaxf(s,0.f);
}

__global__ __launch_bounds__(256) void prenet2_kernel(const float* __restrict__ h1,
    const float* __restrict__ W2, float* __restrict__ pre)
{
  __shared__ float row[256];
  int blk = blockIdx.x;
  int tid = threadIdx.x;
  row[tid] = h1[(size_t)blk*256 + tid];
  __syncthreads();
  float s=0.f;
  for (int c=0;c<256;c++) s += row[c]*W2[c*256+tid];
  pre[(size_t)blk*256 + tid] = fmaxf(s,0.f);
}

// pm[b*400+t][a] = sum_d memory[b][t][d]*memory_W[d][a]
__global__ __launch_bounds__(128) void pm_kernel(const float* __restrict__ memory,
    const float* __restrict__ memory_W, float* __restrict__ pm)
{
  __shared__ float mrow[512];
  int blk = blockIdx.x;  // b*400+t
  int tid = threadIdx.x;
  const float* src = memory + (size_t)blk*512;
  for (int i=tid;i<512;i+=128) mrow[i]=src[i];
  __syncthreads();
  float s=0.f;
  for (int d=0; d<512; d++) s += mrow[d]*memory_W[d*128+tid];
  pm[(size_t)blk*128+tid]=s;
}

__global__ void zero_kernel(float* p, int n){
  int i = blockIdx.x*blockDim.x+threadIdx.x;
  if (i<n) p[i]=0.f;
}

// -------------------- per-step kernels --------------------

// Gp[ks][b][n] partial gates: x = concat(x0,x1,x2) rows=32;  W = [Wih(kih rows); Whh]
// grid (64 colblocks of 64 cols, 4 k-chunks), block 256
__global__ __launch_bounds__(256) void gates_kernel(
    const float* __restrict__ x0, int n0,
    const float* __restrict__ x1, int n1,
    const float* __restrict__ x2, int n2,
    const float* __restrict__ Wih, const float* __restrict__ Whh, int kih,
    float* __restrict__ Gp, int K)
{
  __shared__ float xs[32*66];
  const int nb = blockIdx.x;
  const int ks = blockIdx.y;
  const int chunk = K >> 2;
  const int k_beg = ks*chunk, k_end = k_beg+chunk;
  const int tid = threadIdx.x;
  const int q = tid & 7, row = tid >> 3;
  const int colbase = nb*64;
  float4 acc0 = {0,0,0,0}, acc1 = {0,0,0,0};
  for (int k0 = k_beg; k0 < k_end; k0 += 64){
    __syncthreads();
    for (int i=0;i<8;i++){
      int idx = i*256 + tid;
      int r = idx >> 6, kk = idx & 63;
      int k = k0 + kk;
      float v;
      if (k < n0) v = x0[r*n0 + k];
      else if (k < n0+n1) v = x1[r*n1 + (k-n0)];
      else v = x2[r*n2 + (k-n0-n1)];
      xs[r*66+kk] = v;
    }
    __syncthreads();
    for (int kk=0; kk<64; kk++){
      int k = k0 + kk;
      const float* wrow = (k < kih) ? (Wih + (size_t)k*G4) : (Whh + (size_t)(k-kih)*G4);
      float4 w0 = *(const float4*)(wrow + colbase + q*4);
      float4 w1 = *(const float4*)(wrow + colbase + 32 + q*4);
      float xv = xs[row*66+kk];
      acc0.x += xv*w0.x; acc0.y += xv*w0.y; acc0.z += xv*w0.z; acc0.w += xv*w0.w;
      acc1.x += xv*w1.x; acc1.y += xv*w1.y; acc1.z += xv*w1.z; acc1.w += xv*w1.w;
    }
  }
  float* gp = Gp + (size_t)ks*(32*G4) + (size_t)row*G4;
  *(float4*)(gp + colbase + q*4) = acc0;
  *(float4*)(gp + colbase + 32 + q*4) = acc1;
}

// per-b: reduce att gate partials -> ah/ac; q = ah@query_W; conv+energies; softmax; ctx; awc; aligns
__global__ __launch_bounds__(512) void att_fused_kernel(
    const float* __restrict__ Gp, const float* __restrict__ att_b,
    float* __restrict__ ah, float* __restrict__ ac,
    const float* __restrict__ query_W,
    const float* __restrict__ wc,    // loc_conv_W [32][2][31]
    const float* __restrict__ wd,    // loc_dense_W [32][128]
    const float* __restrict__ vvec,  // [128]
    const float* __restrict__ pm,    // [32][400][128]
    const float* __restrict__ memory,// [32][400][512]
    const int* __restrict__ mlen,
    float* __restrict__ aw, float* __restrict__ awc, float* __restrict__ ctx,
    float* __restrict__ out_aligns, int step)
{
  __shared__ float ah_s[1024];
  __shared__ float aw_s[400], awc_s[400], e_s[400];
  __shared__ float wd_s[32*128];
  __shared__ float wc_s[32*62];
  __shared__ float q_s[128];
  __shared__ float qp[4][128];
  __shared__ float v_s[128];
  __shared__ float red[8];
  int b = blockIdx.x, tid = threadIdx.x;

  for (int i=tid; i<32*128; i+=512) wd_s[i]=wd[i];
  for (int i=tid; i<32*62; i+=512) wc_s[i]=wc[i];
  if (tid<128) v_s[tid]=vvec[tid];
  if (tid<400){ aw_s[tid]=aw[b*400+tid]; awc_s[tid]=awc[b*400+tid]; }

  // LSTM pointwise (2 hidden units per thread)
  for (int u=0; u<2; u++){
    int j = tid + u*512;
    float gi=att_b[j], gf=att_b[1024+j], gg=att_b[2048+j], go=att_b[3072+j];
    for (int s=0;s<4;s++){
      const float* g = Gp + (size_t)s*(32*G4) + (size_t)b*G4;
      gi += g[j]; gf += g[1024+j]; gg += g[2048+j]; go += g[3072+j];
    }
    float c = sigm(gf)*ac[b*1024+j] + sigm(gi)*ftanh(gg);
    float h = sigm(go)*ftanh(c);
    ac[b*1024+j]=c; ah[b*1024+j]=h; ah_s[j]=h;
  }
  __syncthreads();

  // q = ah @ query_W  (split K over 4 slices)
  {
    int a = tid & 127, sl = tid >> 7;
    float s = 0.f;
    int kb = sl*256;
    for (int k=kb; k<kb+256; k++) s += ah_s[k]*query_W[k*128+a];
    qp[sl][a]=s;
  }
  __syncthreads();
  if (tid<128) q_s[tid] = qp[0][tid]+qp[1][tid]+qp[2][tid]+qp[3][tid];
  __syncthreads();

  // energies
  int len = mlen[b];
  float ev = -1e30f;
  if (tid<400 && tid<len){
    int t = tid;
    float cf[32];
    #pragma unroll
    for (int f=0; f<32; f++) cf[f]=0.f;
    for (int k=0;k<31;k++){
      int idx = t + k - 15;
      float a1 = (idx>=0 && idx<400) ? aw_s[idx] : 0.f;
      float a2 = (idx>=0 && idx<400) ? awc_s[idx] : 0.f;
      #pragma unroll
      for (int f=0; f<32; f++)
        cf[f] += wc_s[f*62 + k]*a1 + wc_s[f*62 + 31 + k]*a2;
    }
    float acc=0.f;
    const float* pmrow = pm + (size_t)b*51200 + t*128;
    for (int a=0; a<128; a++){
      float loc=0.f;
      #pragma unroll
      for (int f=0; f<32; f++) loc += cf[f]*wd_s[f*128+a];
      acc += ftanh(q_s[a] + pmrow[a] + loc)*v_s[a];
    }
    ev = acc;
  }
  // block softmax (512 threads)
  float m = ev;
  for (int off=32; off>0; off>>=1) m = fmaxf(m, __shfl_down(m, off, 64));
  if ((tid&63)==0) red[tid>>6]=m;
  __syncthreads();
  if (tid==0){ float mm=red[0]; for(int i=1;i<8;i++) mm=fmaxf(mm,red[i]); red[0]=mm; }
  __syncthreads();
  m = red[0];
  __syncthreads();
  float ex = (tid<400) ? __expf(ev-m) : 0.f;
  float ssum = ex;
  for (int off=32; off>0; off>>=1) ssum += __shfl_down(ssum, off, 64);
  if ((tid&63)==0) red[tid>>6]=ssum;
  __syncthreads();
  if (tid==0){ float s2=0.f; for(int i=0;i<8;i++) s2+=red[i]; red[0]=s2; }
  __syncthreads();
  float inv = 1.f/red[0];
  if (tid<400){
    float a_new = ex*inv;
    e_s[tid] = a_new;
    aw[b*400+tid] = a_new;
    awc[b*400+tid] = awc_s[tid] + a_new;
    out_aligns[(size_t)b*160000 + step*400 + tid] = a_new;
  }
  __syncthreads();
  // ctx[b][d] = sum_t aw[t]*memory[b][t][d]
  {
    float s=0.f;
    const float* mrow = memory + (size_t)b*204800 + tid;
    for (int t=0;t<400;t++) s += e_s[t]*mrow[t*512];
    ctx[b*512+tid]=s;
  }
}

// per-b: reduce dec gate partials -> dh/dc; mel/gate projections
__global__ __launch_bounds__(256) void dec_pw_proj_kernel(
    const float* __restrict__ Gp, const float* __restrict__ dec_b,
    float* __restrict__ dh, float* __restrict__ dc,
    const float* __restrict__ ctx,
    const float* __restrict__ proj_W, const float* __restrict__ proj_b,
    const float* __restrict__ gate_W, const float* __restrict__ gate_b,
    float* __restrict__ out, int step)
{
  __shared__ float do_s[1536];
  __shared__ float pp[3][81];
  int b = blockIdx.x, tid = threadIdx.x;
  for (int u=0;u<4;u++){
    int j = tid + u*256;
    float gi=dec_b[j], gf=dec_b[1024+j], gg=dec_b[2048+j], go=dec_b[3072+j];
    for (int s=0;s<4;s++){
      const float* g = Gp + (size_t)s*(32*G4) + (size_t)b*G4;
      gi+=g[j]; gf+=g[1024+j]; gg+=g[2048+j]; go+=g[3072+j];
    }
    float c = sigm(gf)*dc[b*1024+j] + sigm(gi)*ftanh(gg);
    float h = sigm(go)*ftanh(c);
    dc[b*1024+j]=c; dh[b*1024+j]=h; do_s[j]=h;
  }
  do_s[1024+tid]     = ctx[b*512+tid];
  do_s[1024+256+tid] = ctx[b*512+256+tid];
  __syncthreads();
  int sl = tid / 81, o = tid - sl*81;   // 243 active
  if (sl < 3){
    float s=0.f;
    int kb = sl*512;
    for (int k=kb; k<kb+512; k++){
      float w = (o<80) ? proj_W[k*80+o] : gate_W[k];
      s += do_s[k]*w;
    }
    pp[sl][o]=s;
  }
  __syncthreads();
  if (tid < 81){
    float r = pp[0][tid]+pp[1][tid]+pp[2][tid];
    if (tid<80) out[(size_t)b*32000 + tid*400 + step] = r + proj_b[tid];
    else        out[1024000 + b*400 + step] = r + gate_b[0];
  }
}

// -------------------- launch --------------------

extern "C" void kernel_launch(void* const* d_in, const int* in_sizes, int n_in,
                              void* d_out, int out_size, void* d_ws, size_t ws_size,
                              hipStream_t stream) {
  const float* memory      = (const float*)d_in[0];
  const float* mel_target  = (const float*)d_in[1];
  const int*   mlen        = (const int*)  d_in[2];
  const float* prenet_W1   = (const float*)d_in[3];
  const float* prenet_W2   = (const float*)d_in[4];
  const float* query_W     = (const float*)d_in[5];
  const float* memory_W    = (const float*)d_in[6];
  const float* weight_vec  = (const float*)d_in[7];
  const float* loc_conv_W  = (const float*)d_in[8];
  const float* loc_dense_W = (const float*)d_in[9];
  const float* att_Wih     = (const float*)d_in[10];
  const float* att_Whh     = (const float*)d_in[11];
  const float* att_b       = (const float*)d_in[12];
  const float* dec_Wih     = (const float*)d_in[13];
  const float* dec_Whh     = (const float*)d_in[14];
  const float* dec_b       = (const float*)d_in[15];
  const float* proj_W      = (const float*)d_in[16];
  const float* proj_b      = (const float*)d_in[17];
  const float* gate_W      = (const float*)d_in[18];
  const float* gate_b      = (const float*)d_in[19];
  float* out = (float*)d_out;
  float* ws  = (float*)d_ws;

  float* PRE  = ws;                 // [400][32][256]
  float* PM   = ws + 3276800;       // [32][400][128]
  float* H1   = ws + 4915200;       // [400][32][256]
  float* GATT = ws + 8192000;       // [4][32][4096]
  float* GDEC = ws + 8716288;       // [4][32][4096]
  float* AH   = ws + 9240576;       // [32][1024]
  float* AC   = AH + 32768;
  float* DH   = AC + 32768;
  float* DC   = DH + 32768;
  float* AW   = DC + 32768;         // [32][400]
  float* AWC  = AW + 12800;
  float* CTX  = AWC + 12800;        // [32][512]
  const int state_n = 4*32768 + 2*12800 + 16384;

  hipLaunchKernelGGL(zero_kernel, dim3((state_n+255)/256), dim3(256), 0, stream, AH, state_n);
  hipLaunchKernelGGL(prenet1_kernel, dim3(12800), dim3(256), 0, stream, mel_target, prenet_W1, H1);
  hipLaunchKernelGGL(prenet2_kernel, dim3(12800), dim3(256), 0, stream, H1, prenet_W2, PRE);
  hipLaunchKernelGGL(pm_kernel, dim3(12800), dim3(128), 0, stream, memory, memory_W, PM);

  for (int t=0; t<400; t++){
    hipLaunchKernelGGL(gates_kernel, dim3(64,4), dim3(256), 0, stream,
        PRE + (size_t)t*8192, 256, CTX, 512, AH, 1024,
        att_Wih, att_Whh, 768, GATT, 1792);
    hipLaunchKernelGGL(att_fused_kernel, dim3(32), dim3(512), 0, stream,
        GATT, att_b, AH, AC, query_W, loc_conv_W, loc_dense_W, weight_vec,
        PM, memory, mlen, AW, AWC, CTX, out + 1036800, t);
    hipLaunchKernelGGL(gates_kernel, dim3(64,4), dim3(256), 0, stream,
        AH, 1024, CTX, 512, DH, 1024,
        dec_Wih, dec_Whh, 1536, GDEC, 2560);
    hipLaunchKernelGGL(dec_pw_proj_kernel, dim3(32), dim3(256), 0, stream,
        GDEC, dec_b, DH, DC, CTX, proj_W, proj_b, gate_W, gate_b, out, t);
  }
}